// Round 1
// baseline (2370.364 us; speedup 1.0000x reference)
//
#include <hip/hip_runtime.h>
#include <cstdint>
#include <cstddef>

// GraphConvolution: out = (A_sparse @ x) @ W^T + b
// N=100000 nodes, E=3.2M edges, D=256.
// Pipeline: histogram -> scan -> CSR scatter -> fused gather+linear.
#define D 256
#define NPB 32          // nodes per fused block
#define SCAN_CHUNK 2048 // 256 threads * 8 items

__global__ void k_hist(const int* __restrict__ erow, int* __restrict__ counts, int e) {
    int i = blockIdx.x * blockDim.x + threadIdx.x;
    if (i < e) atomicAdd(&counts[erow[i]], 1);
}

__global__ void k_scan1(const int* __restrict__ counts, int* __restrict__ row_start,
                        int* __restrict__ blk_sums, int n) {
    __shared__ int sd[256];
    int tid = threadIdx.x;
    int base = blockIdx.x * SCAN_CHUNK + tid * 8;
    int v[8];
    int s = 0;
#pragma unroll
    for (int i = 0; i < 8; ++i) {
        int idx = base + i;
        v[i] = (idx < n) ? counts[idx] : 0;
        s += v[i];
    }
    sd[tid] = s;
    __syncthreads();
    // Hillis-Steele inclusive scan over 256 thread sums
    for (int off = 1; off < 256; off <<= 1) {
        int t = (tid >= off) ? sd[tid - off] : 0;
        __syncthreads();
        sd[tid] += t;
        __syncthreads();
    }
    int run = sd[tid] - s;  // exclusive prefix of this thread within chunk
    if (tid == 255) blk_sums[blockIdx.x] = sd[255];
#pragma unroll
    for (int i = 0; i < 8; ++i) {
        int idx = base + i;
        if (idx < n) row_start[idx] = run;
        run += v[i];
    }
}

// exclusive scan of per-chunk totals (nch <= 64 here: 49 chunks)
__global__ void k_scan2(int* __restrict__ blk_sums, int* __restrict__ row_start, int nch, int n) {
    __shared__ int sd[64];
    int tid = threadIdx.x;
    if (tid < nch) sd[tid] = blk_sums[tid];
    __syncthreads();
    if (tid == 0) {
        int run = 0;
        for (int b = 0; b < nch; ++b) { int t = sd[b]; sd[b] = run; run += t; }
        row_start[n] = run;  // == E
    }
    __syncthreads();
    if (tid < nch) blk_sums[tid] = sd[tid];
}

__global__ void k_scan3(int* __restrict__ row_start, const int* __restrict__ blk_sums, int n) {
    int i = blockIdx.x * blockDim.x + threadIdx.x;
    if (i < n) row_start[i] += blk_sums[i >> 11];  // / SCAN_CHUNK
}

__global__ void k_scatter(const int* __restrict__ erow, const int* __restrict__ ecol,
                          const float* __restrict__ eval, const int* __restrict__ row_start,
                          int* __restrict__ cursor, int2* __restrict__ sedge, int e) {
    int i = blockIdx.x * blockDim.x + threadIdx.x;
    if (i < e) {
        int r = erow[i];
        int p = row_start[r] + atomicAdd(&cursor[r], 1);
        sedge[p] = make_int2(ecol[i], __float_as_int(eval[i]));
    }
}

// Fused: per block, gather 32 node rows (atomic-free, CSR) into LDS, then
// register-blocked fp32 GEMM vs W (staged in 16-wide k-chunks in LDS).
__global__ __launch_bounds__(256) void k_fused(
    const float* __restrict__ x, const int2* __restrict__ sedge,
    const int* __restrict__ row_start, const float* __restrict__ W,
    const float* __restrict__ bias, float* __restrict__ out, int n) {
    // 32*260*4 = 33280 B ; 256*20*4 = 20480 B ; total 53760 B -> 3 blocks/CU
    __shared__ __align__(16) float agg_s[NPB][D + 4];
    __shared__ __align__(16) float wsm[256][20];  // W tile [o][16k + 4 pad]

    const int tid = threadIdx.x;
    const int lane = tid & 63;
    const int wv = tid >> 6;

    // ---------- phase 1: gather (one wave = 8 nodes, sequential) ----------
    for (int mm = 0; mm < NPB / 4; ++mm) {
        int m = wv * (NPB / 4) + mm;
        int node = blockIdx.x * NPB + m;
        float4 acc = make_float4(0.f, 0.f, 0.f, 0.f);
        if (node < n) {
            int e0 = row_start[node];
            int e1 = row_start[node + 1];
            const float4* xb = (const float4*)x;
            for (int e = e0; e < e1; ++e) {
                int2 ev = sedge[e];
                float v = __int_as_float(ev.y);
                float4 xv = xb[(size_t)ev.x * (D / 4) + lane];  // coalesced 1KB/wave
                acc.x += v * xv.x;
                acc.y += v * xv.y;
                acc.z += v * xv.z;
                acc.w += v * xv.w;
            }
        }
        *(float4*)&agg_s[m][lane * 4] = acc;  // b128, conflict-free (row pad 260)
    }
    __syncthreads();

    // ---------- phase 2: out[m][o] = sum_k agg[m][k] * W[o][k]  (+ bias) ----------
    const int tx = tid & 15;   // o = tx + 16*i
    const int ty = tid >> 4;   // m = ty*2 + j
    float acc2[2][16];
#pragma unroll
    for (int j = 0; j < 2; ++j)
#pragma unroll
        for (int i = 0; i < 16; ++i) acc2[j][i] = 0.f;

    for (int kc = 0; kc < 16; ++kc) {  // k chunks of 16
        __syncthreads();
        // stage W[0..255][kc*16 .. +15]: thread -> o = tid/4 + 64r, kk = (tid&3)*4
#pragma unroll
        for (int r = 0; r < 4; ++r) {
            int o = (tid >> 2) + (r << 6);
            int kk = (tid & 3) << 2;
            float4 wv4 = *(const float4*)&W[(size_t)o * D + kc * 16 + kk];
            *(float4*)&wsm[o][kk] = wv4;
        }
        __syncthreads();
#pragma unroll
        for (int k4 = 0; k4 < 4; ++k4) {
            float4 a0 = *(const float4*)&agg_s[ty * 2 + 0][kc * 16 + k4 * 4];
            float4 a1 = *(const float4*)&agg_s[ty * 2 + 1][kc * 16 + k4 * 4];
#pragma unroll
            for (int i = 0; i < 16; ++i) {
                float4 w4 = *(const float4*)&wsm[tx + 16 * i][k4 * 4];
                acc2[0][i] += a0.x * w4.x + a0.y * w4.y + a0.z * w4.z + a0.w * w4.w;
                acc2[1][i] += a1.x * w4.x + a1.y * w4.y + a1.z * w4.z + a1.w * w4.w;
            }
        }
    }

    // epilogue: coalesced scalar stores (lanes tx consecutive)
#pragma unroll
    for (int j = 0; j < 2; ++j) {
        int node = blockIdx.x * NPB + ty * 2 + j;
        if (node < n) {
            float* op = out + (size_t)node * D;
#pragma unroll
            for (int i = 0; i < 16; ++i) {
                int o = tx + 16 * i;
                op[o] = acc2[j][i] + bias[o];
            }
        }
    }
}

extern "C" void kernel_launch(void* const* d_in, const int* in_sizes, int n_in,
                              void* d_out, int out_size, void* d_ws, size_t ws_size,
                              hipStream_t stream) {
    const float* x    = (const float*)d_in[0];
    const int*   erow = (const int*)d_in[1];
    const int*   ecol = (const int*)d_in[2];
    const float* eval = (const float*)d_in[3];
    const float* W    = (const float*)d_in[4];
    const float* bias = (const float*)d_in[5];
    float* out = (float*)d_out;

    const int n = in_sizes[0] / D;  // 100000
    const int e = in_sizes[1];      // 3200000

    // workspace layout (~27 MB): counts[n] | cursor[n] | blk_sums[64] | row_start[n+1] | sedge[e]
    int* counts    = (int*)d_ws;
    int* cursor    = counts + n;
    int* blk_sums  = cursor + n;
    int* row_start = blk_sums + 64;
    int2* sedge    = (int2*)(((uintptr_t)(row_start + n + 1) + 15) & ~(uintptr_t)15);

    // zero counts + cursor + blk_sums (ws is poisoned 0xAA every call)
    hipMemsetAsync(counts, 0, (size_t)(2 * n + 64) * sizeof(int), stream);

    const int nch = (n + SCAN_CHUNK - 1) / SCAN_CHUNK;  // 49

    k_hist<<<(e + 255) / 256, 256, 0, stream>>>(erow, counts, e);
    k_scan1<<<nch, 256, 0, stream>>>(counts, row_start, blk_sums, n);
    k_scan2<<<1, 64, 0, stream>>>(blk_sums, row_start, nch, n);
    k_scan3<<<(n + 255) / 256, 256, 0, stream>>>(row_start, blk_sums, n);
    k_scatter<<<(e + 255) / 256, 256, 0, stream>>>(erow, ecol, eval, row_start, cursor, sedge, e);
    k_fused<<<(n + NPB - 1) / NPB, 256, 0, stream>>>(x, sedge, row_start, W, bias, out, n);
}